// Round 3
// baseline (168.565 us; speedup 1.0000x reference)
//
#include <hip/hip_runtime.h>
#include <math.h>

#define BS 8
#define SEQ 1024
#define DIM 1024
#define FF 4096
#define NE 8
#define NSLOT 16
#define MAXM 8
#define NCHUNK 64

#define UG_ROWS 32     // rows of w1 (and w3) per kupgate block
#define UG_PAIRS 8     // 8 pairs x 4 rows
#define DN_ROWS 16     // rows of w2 per kdown block

// ws layout in floats
#define WS_PARTIAL 0                                  // [BS][NCHUNK][DIM]
#define WS_SELW    (WS_PARTIAL + BS*NCHUNK*DIM)
#define WS_SELE    (WS_SELW + NSLOT)
#define WS_ACT     (WS_SELE + NSLOT)                  // [NSLOT][FF]
#define WS_Y       (WS_ACT + NSLOT*FF)                // [NSLOT][DIM]

__device__ __forceinline__ float dot4(float4 a, float4 b) {
    return a.x*b.x + a.y*b.y + a.z*b.z + a.w*b.w;
}

// async global->LDS, 16 B per lane; gptr is per-lane, lptr wave-uniform
__device__ __forceinline__ void async16(const float* g, float* l) {
    __builtin_amdgcn_global_load_lds(
        (const __attribute__((address_space(1))) unsigned int*)g,
        (__attribute__((address_space(3))) unsigned int*)l,
        16, 0, 0);
}

// ---- 1. partial sums over L for the sequence mean ----
__global__ __launch_bounds__(256) void kmean(const float4* __restrict__ h4,
                                             float4* __restrict__ part4) {
    const int c = blockIdx.x, b = blockIdx.y, t = threadIdx.x;
    const int LPER = SEQ / NCHUNK;  // 16
    const float4* p = h4 + ((size_t)b * SEQ + (size_t)c * LPER) * (DIM/4) + t;
    float4 a = make_float4(0.f, 0.f, 0.f, 0.f);
    #pragma unroll
    for (int i = 0; i < LPER; ++i) {
        float4 v = p[(size_t)i * (DIM/4)];
        a.x += v.x; a.y += v.y; a.z += v.z; a.w += v.w;
    }
    part4[((size_t)(b * NCHUNK + c)) * (DIM/4) + t] = a;
}

// ---- 2. reduce partials -> hbar -> logits -> softmax -> top2 (fused) ----
__global__ __launch_bounds__(256) void krouter(const float4* __restrict__ part4,
                                               const float4* __restrict__ rw4,
                                               float* __restrict__ out_logits,
                                               float* __restrict__ selw,
                                               int* __restrict__ sele) {
    const int b = blockIdx.x, t = threadIdx.x;
    const float4* p = part4 + (size_t)b * NCHUNK * (DIM/4) + t;
    float4 s = make_float4(0.f, 0.f, 0.f, 0.f);
    #pragma unroll 4
    for (int c = 0; c < NCHUNK; ++c) {
        float4 v = p[(size_t)c * (DIM/4)];
        s.x += v.x; s.y += v.y; s.z += v.z; s.w += v.w;
    }
    const float inv = 1.0f / (float)SEQ;
    s.x *= inv; s.y *= inv; s.z *= inv; s.w *= inv;

    __shared__ float red[4];
    __shared__ float lg[NE];
    const int wave = t >> 6, lane = t & 63;
    for (int e = 0; e < NE; ++e) {
        float4 w = rw4[(size_t)e * (DIM/4) + t];
        float pd = dot4(s, w);
        #pragma unroll
        for (int o = 32; o; o >>= 1) pd += __shfl_xor(pd, o);
        if (lane == 0) red[wave] = pd;
        __syncthreads();
        if (t == 0) {
            float l = red[0] + red[1] + red[2] + red[3];
            lg[e] = l;
            out_logits[b * NE + e] = l;
        }
        __syncthreads();
    }
    if (t == 0) {
        float l[NE];
        float mx = -1e30f;
        #pragma unroll
        for (int e = 0; e < NE; ++e) { l[e] = lg[e]; mx = fmaxf(mx, l[e]); }
        float sum = 0.f;
        #pragma unroll
        for (int e = 0; e < NE; ++e) { l[e] = expf(l[e] - mx); sum += l[e]; }
        const float invs = 1.f / sum;
        float v1 = -1.f, v2 = -1.f; int e1 = -1, e2 = -1;
        #pragma unroll
        for (int e = 0; e < NE; ++e) {
            float pe = l[e] * invs;
            if (pe > v1)      { v2 = v1; e2 = e1; v1 = pe; e1 = e; }
            else if (pe > v2) { v2 = pe; e2 = e; }
        }
        selw[b * 2 + 0] = v1; sele[b * 2 + 0] = e1;
        selw[b * 2 + 1] = v2; sele[b * 2 + 1] = e2;
    }
}

__device__ __forceinline__ int build_slots(const int* __restrict__ sele, int e, int* slot) {
    unsigned mask = 0;
    #pragma unroll
    for (int s = 0; s < NSLOT; ++s) mask |= (sele[s] == e) ? (1u << s) : 0u;
    const int m = __popc(mask);
    unsigned mm = mask;
    #pragma unroll
    for (int ti = 0; ti < MAXM; ++ti) { slot[ti] = __ffs(mm) - 1; mm &= mm - 1; }
    return m;
}

// ---- 3. up/gate + SiLU, async-pipelined weight stream ----
// LDS: xs[8][1024] (32KB) + wb ring-2 of (4 w1-rows + 4 w3-rows) (64KB) = 96KB
template<int M>
__device__ void upgate_work(const float* __restrict__ h,
                            const float* __restrict__ w1e,
                            const float* __restrict__ w3e,
                            float* __restrict__ act,
                            const int* slot, int tile, int t,
                            float* xs, float* wb) {
    const int wave = t >> 6, lane = t & 63;
    const int row0 = tile * UG_ROWS;

    // stage x slices into LDS (plain ds_write), 32 threads per slot
    {
        const int ti = t >> 5, j = t & 31;
        if (ti < M) {
            const int s = slot[ti];
            const float4* src = (const float4*)(h + ((size_t)((s >> 1) * SEQ + (s & 1))) * DIM);
            float4* dst = (float4*)(xs + ti * 1024);
            #pragma unroll
            for (int i = 0; i < 8; ++i) dst[j + i * 32] = src[j + i * 32];
        }
    }
    __syncthreads();   // safe: no async loads outstanding yet

    auto stage = [&](int p) {
        const size_t rbase = (size_t)(row0 + p * 4 + wave) * DIM + lane * 4;
        const float* g1 = w1e + rbase;
        const float* g3 = w3e + rbase;
        float* l1 = wb + (p & 1) * 8192 + wave * 1024;
        float* l3 = wb + (p & 1) * 8192 + 4096 + wave * 1024;
        #pragma unroll
        for (int r = 0; r < 4; ++r) {
            async16(g1 + r * 256, l1 + r * 256);
            async16(g3 + r * 256, l3 + r * 256);
        }
    };

    stage(0);
    for (int p = 0; p < UG_PAIRS; ++p) {
        if (p + 1 < UG_PAIRS) {
            stage(p + 1);                                   // 8 instr/wave
            asm volatile("s_waitcnt vmcnt(8)" ::: "memory"); // pair p landed
        } else {
            asm volatile("s_waitcnt vmcnt(0)" ::: "memory");
        }
        __builtin_amdgcn_s_barrier();
        __builtin_amdgcn_sched_barrier(0);

        const float4* f1p = (const float4*)(wb + (p & 1) * 8192 + wave * 1024);
        const float4* f3p = (const float4*)(wb + (p & 1) * 8192 + 4096 + wave * 1024);
        float up[M], gt[M];
        #pragma unroll
        for (int ti = 0; ti < M; ++ti) { up[ti] = 0.f; gt[ti] = 0.f; }
        #pragma unroll
        for (int c = 0; c < 4; ++c) {
            float4 f1 = f1p[c * 64 + lane];
            float4 f3 = f3p[c * 64 + lane];
            #pragma unroll
            for (int ti = 0; ti < M; ++ti) {
                float4 xf = ((const float4*)(xs + ti * 1024))[c * 64 + lane];
                up[ti] += dot4(f1, xf);
                gt[ti] += dot4(f3, xf);
            }
        }
        #pragma unroll
        for (int ti = 0; ti < M; ++ti) {
            float u = up[ti], g = gt[ti];
            #pragma unroll
            for (int o = 32; o; o >>= 1) { u += __shfl_xor(u, o); g += __shfl_xor(g, o); }
            if (lane == 0)
                act[(size_t)slot[ti] * FF + row0 + p * 4 + wave] =
                    (u / (1.f + expf(-u))) * g;
        }
        __builtin_amdgcn_sched_barrier(0);
        __builtin_amdgcn_s_barrier();
    }
}

__global__ __launch_bounds__(256) void kupgate(const float* __restrict__ h,
                                               const float* __restrict__ w1,
                                               const float* __restrict__ w3,
                                               const int* __restrict__ sele,
                                               float* __restrict__ act) {
    __shared__ float xs[MAXM * 1024];      // 32 KB
    __shared__ float wb[2 * 8192];         // 64 KB ring
    const int e = blockIdx.y, tile = blockIdx.x, t = threadIdx.x;
    int slot[MAXM];
    const int m = build_slots(sele, e, slot);
    if (m == 0) return;
    const float* w1e = w1 + (size_t)e * FF * DIM;
    const float* w3e = w3 + (size_t)e * FF * DIM;
    switch (m) {
        case 1: upgate_work<1>(h, w1e, w3e, act, slot, tile, t, xs, wb); break;
        case 2: upgate_work<2>(h, w1e, w3e, act, slot, tile, t, xs, wb); break;
        case 3: upgate_work<3>(h, w1e, w3e, act, slot, tile, t, xs, wb); break;
        case 4: upgate_work<4>(h, w1e, w3e, act, slot, tile, t, xs, wb); break;
        case 5: upgate_work<5>(h, w1e, w3e, act, slot, tile, t, xs, wb); break;
        case 6: upgate_work<6>(h, w1e, w3e, act, slot, tile, t, xs, wb); break;
        case 7: upgate_work<7>(h, w1e, w3e, act, slot, tile, t, xs, wb); break;
        default: upgate_work<8>(h, w1e, w3e, act, slot, tile, t, xs, wb); break;
    }
}

// ---- 4. down projection, async-pipelined, K chunked by 1024 ----
// LDS: as[8][1024] (32KB) + wb ring-2 of 4-row chunks (32KB) = 64KB
template<int M>
__device__ void down_work(const float* __restrict__ w2e,
                          const float* __restrict__ act,
                          const float* __restrict__ selw,
                          float* __restrict__ y,
                          const int* slot, int tile, int t,
                          float* as, float* wb) {
    const int wave = t >> 6, lane = t & 63;
    const int row0 = tile * DN_ROWS;

    float acc[4][M];
    #pragma unroll
    for (int p = 0; p < 4; ++p)
        #pragma unroll
        for (int ti = 0; ti < M; ++ti) acc[p][ti] = 0.f;

    auto stagew = [&](int kc_, int p_) {
        const float* g = w2e + (size_t)(row0 + p_ * 4 + wave) * FF + kc_ * 1024 + lane * 4;
        float* l = wb + (p_ & 1) * 4096 + wave * 1024;
        #pragma unroll
        for (int r = 0; r < 4; ++r) async16(g + r * 256, l + r * 256);
    };

    for (int kc = 0; kc < 4; ++kc) {
        // stage act chunk: wave stages quarter `wave` of each slot's 4KB chunk (M instr)
        #pragma unroll
        for (int ti = 0; ti < M; ++ti) {
            const float* g = act + (size_t)slot[ti] * FF + kc * 1024 + wave * 256 + lane * 4;
            async16(g, as + ti * 1024 + wave * 256);
        }
        stagew(kc, 0);                                       // 4 instr/wave
        #pragma unroll
        for (int p = 0; p < 4; ++p) {
            if (p < 3) {
                stagew(kc, p + 1);                           // 4 instr/wave
                asm volatile("s_waitcnt vmcnt(4)" ::: "memory"); // act+pair p landed
            } else {
                asm volatile("s_waitcnt vmcnt(0)" ::: "memory");
            }
            __builtin_amdgcn_s_barrier();
            __builtin_amdgcn_sched_barrier(0);

            const float4* wf4 = (const float4*)(wb + (p & 1) * 4096 + wave * 1024);
            #pragma unroll
            for (int c = 0; c < 4; ++c) {
                float4 wf = wf4[c * 64 + lane];
                #pragma unroll
                for (int ti = 0; ti < M; ++ti) {
                    float4 af = ((const float4*)(as + ti * 1024))[c * 64 + lane];
                    acc[p][ti] += dot4(wf, af);
                }
            }
            __builtin_amdgcn_sched_barrier(0);
            __builtin_amdgcn_s_barrier();
        }
    }

    #pragma unroll
    for (int p = 0; p < 4; ++p)
        #pragma unroll
        for (int ti = 0; ti < M; ++ti) {
            float v = acc[p][ti];
            #pragma unroll
            for (int o = 32; o; o >>= 1) v += __shfl_xor(v, o);
            if (lane == 0)
                y[(size_t)slot[ti] * DIM + row0 + p * 4 + wave] = selw[slot[ti]] * v;
        }
}

__global__ __launch_bounds__(256) void kdown(const float* __restrict__ w2,
                                             const float* __restrict__ act,
                                             const int* __restrict__ sele,
                                             const float* __restrict__ selw,
                                             float* __restrict__ y) {
    __shared__ float as[MAXM * 1024];     // 32 KB
    __shared__ float wb[2 * 4096];        // 32 KB ring
    const int e = blockIdx.y, tile = blockIdx.x, t = threadIdx.x;
    int slot[MAXM];
    const int m = build_slots(sele, e, slot);
    if (m == 0) return;
    const float* w2e = w2 + (size_t)e * DIM * FF;
    switch (m) {
        case 1: down_work<1>(w2e, act, selw, y, slot, tile, t, as, wb); break;
        case 2: down_work<2>(w2e, act, selw, y, slot, tile, t, as, wb); break;
        case 3: down_work<3>(w2e, act, selw, y, slot, tile, t, as, wb); break;
        case 4: down_work<4>(w2e, act, selw, y, slot, tile, t, as, wb); break;
        case 5: down_work<5>(w2e, act, selw, y, slot, tile, t, as, wb); break;
        case 6: down_work<6>(w2e, act, selw, y, slot, tile, t, as, wb); break;
        case 7: down_work<7>(w2e, act, selw, y, slot, tile, t, as, wb); break;
        default: down_work<8>(w2e, act, selw, y, slot, tile, t, as, wb); break;
    }
}

// ---- 5. combine two selections per batch, broadcast across L ----
__global__ __launch_bounds__(256) void kbcast(const float4* __restrict__ y4,
                                              float4* __restrict__ out4) {
    const int b = blockIdx.y, lg = blockIdx.x, t = threadIdx.x;
    float4 y0 = y4[(size_t)(2 * b) * (DIM/4) + t];
    float4 y1 = y4[(size_t)(2 * b + 1) * (DIM/4) + t];
    float4 c = make_float4(y0.x + y1.x, y0.y + y1.y, y0.z + y1.z, y0.w + y1.w);
    size_t base = ((size_t)b * SEQ + (size_t)lg * 8) * (DIM/4) + t;
    #pragma unroll
    for (int i = 0; i < 8; ++i) out4[base + (size_t)i * (DIM/4)] = c;
}

extern "C" void kernel_launch(void* const* d_in, const int* in_sizes, int n_in,
                              void* d_out, int out_size, void* d_ws, size_t ws_size,
                              hipStream_t stream) {
    const float* h  = (const float*)d_in[0];
    const float* rw = (const float*)d_in[1];
    const float* w1 = (const float*)d_in[2];
    const float* w2 = (const float*)d_in[3];
    const float* w3 = (const float*)d_in[4];
    float* out = (float*)d_out;
    float* ws  = (float*)d_ws;

    float* part   = ws + WS_PARTIAL;
    float* selw   = ws + WS_SELW;
    int*   sele   = (int*)(ws + WS_SELE);
    float* act    = ws + WS_ACT;
    float* y      = ws + WS_Y;
    float* out_logits = out + (size_t)BS * SEQ * DIM;

    kmean  <<<dim3(NCHUNK, BS), 256, 0, stream>>>((const float4*)h, (float4*)part);
    krouter<<<BS, 256, 0, stream>>>((const float4*)part, (const float4*)rw, out_logits, selw, sele);
    kupgate<<<dim3(FF / UG_ROWS, NE), 256, 0, stream>>>(h, w1, w3, sele, act);
    kdown  <<<dim3(DIM / DN_ROWS, NE), 256, 0, stream>>>(w2, act, sele, selw, y);
    kbcast <<<dim3(SEQ / 8, BS), 256, 0, stream>>>((const float4*)y, (float4*)out);
}